// Round 2
// baseline (660.458 us; speedup 1.0000x reference)
//
#include <hip/hip_runtime.h>

// Problem constants
#define B_     2
#define P_TOT  4000
#define NP_TOT 4096
#define D_     64
#define M_     512
#define HW_TOT 214272   // 496*432
#define J4     53568    // HW/4

// Output offsets (in floats, concatenated return order)
#define O0 0UL            // spatial_features        [2,128,HW]
#define O1 54853632UL     // spatial_features_point  [2,128,HW]
#define O2 109707264UL    // spatial_scale_features  [2,64,HW]
#define O3 137134080UL    // point_positive_features [8000,64]
#define O4 137646080UL    // memory_positive_features[8000,64]

typedef __attribute__((ext_vector_type(8))) short bb8;
typedef __attribute__((ext_vector_type(4))) float f32x4;

// Sorted-descending insert into top-8 registers (caller guards with sc > s[7])
__device__ __forceinline__ void insert8(float sc, int n, float s[8], int ix[8]) {
  float cs = sc; int ci = n;
#pragma unroll
  for (int i = 0; i < 8; ++i) {
    bool gt = cs > s[i];
    float ts = s[i]; int ti = ix[i];
    s[i]  = gt ? cs : ts;  ix[i] = gt ? ci : ti;
    cs    = gt ? ts : cs;  ci    = gt ? ti : ci;
  }
}

__device__ __forceinline__ void split_bf16(float x, short& h, short& l) {
  unsigned fb = __float_as_uint(x);
  unsigned hb = fb & 0xFFFF0000u;          // truncate to bf16 (hi plane)
  float lof = x - __uint_as_float(hb);     // residual
  h = (short)(hb >> 16);
  l = (short)(__float_as_uint(lof) >> 16); // bf16 of residual (lo plane)
}

// prep: fused [cvt points planes (blocks 0..511)] + [build_owner (512..543)]
//       + [cvt W planes (544..575)]. cvt arithmetic FROZEN since R2.
__global__ __launch_bounds__(256) void prep(
    const float* __restrict__ points, short* __restrict__ hi, short* __restrict__ lo,
    const int* __restrict__ indices, int* __restrict__ owner,
    const float* __restrict__ W, short* __restrict__ whi, short* __restrict__ wlo)
{
  if (blockIdx.x < 512) {
    int t = blockIdx.x * 256 + threadIdx.x;           // n4 = 131072 exactly
    float4 v = ((const float4*)points)[t];
    float x[4] = {v.x, v.y, v.z, v.w};
    short h[4], l[4];
#pragma unroll
    for (int j = 0; j < 4; ++j) split_bf16(x[j], h[j], l[j]);
    ((short4*)hi)[t] = make_short4(h[0], h[1], h[2], h[3]);
    ((short4*)lo)[t] = make_short4(l[0], l[1], l[2], l[3]);
  } else if (blockIdx.x < 544) {
    int t = (blockIdx.x - 512) * 256 + threadIdx.x;
    if (t >= B_ * P_TOT) return;
    int b = (t >= P_TOT) ? 1 : 0;
    int p = t - b * P_TOT;
    atomicMax(&owner[b * HW_TOT + indices[t]], p);
  } else {
    int t = (blockIdx.x - 544) * 256 + threadIdx.x;   // n4 = 8192 exactly
    float4 v = ((const float4*)W)[t];
    float x[4] = {v.x, v.y, v.z, v.w};
    short h[4], l[4];
#pragma unroll
    for (int j = 0; j < 4; ++j) split_bf16(x[j], h[j], l[j]);
    ((short4*)whi)[t] = make_short4(h[0], h[1], h[2], h[3]);
    ((short4*)wlo)[t] = make_short4(l[0], l[1], l[2], l[3]);
  }
}

// MFMA top-8, both branches. blockIdx.y in [0,8): points chunks of 512 (3-term
// split, FROZEN arithmetic since R2). blockIdx.y in [8,16): memory chunks of 64
// W-rows (4-term split: adds the two Al*Bl MFMAs first -> products exact in
// fp32, only accumulation-order noise ~2e-5 vs the old fp32-VALU scores).
// Zero LDS; identical register profile on both paths (R6 lesson: never merge
// paths with different resource footprints — this merge keeps them equal).
__global__ __launch_bounds__(256) void topk_mfma(
    const float* __restrict__ pillars,
    const short* __restrict__ phi, const short* __restrict__ plo,
    const short* __restrict__ whi, const short* __restrict__ wlo,
    float* __restrict__ ws_pts_sc, int* __restrict__ ws_pts_ix,
    float* __restrict__ ws_mem_sc, int* __restrict__ ws_mem_ix)
{
  const int tid = threadIdx.x;
  const int pt = blockIdx.x, chy = blockIdx.y, b = blockIdx.z;
  const bool is_mem = chy >= 8;
  const int ch = is_mem ? (chy - 8) : chy;
  const int lane = tid & 63, wv = tid >> 6;
  const int sub = lane & 15, quad = lane >> 4;

  int prow = pt * 64 + wv * 16 + sub;
  if (prow >= P_TOT) prow = P_TOT - 1;
  const float* ap = pillars + ((size_t)(b * P_TOT) + prow) * D_;
  bb8 Ah0, Ah1, Al0, Al1;
  {
    const float4* a4 = (const float4*)(ap + quad * 8);
    const float4* b4 = (const float4*)(ap + 32 + quad * 8);
    float4 t0 = a4[0], t1 = a4[1], t2 = b4[0], t3 = b4[1];
    float av[16] = {t0.x, t0.y, t0.z, t0.w, t1.x, t1.y, t1.z, t1.w,
                    t2.x, t2.y, t2.z, t2.w, t3.x, t3.y, t3.z, t3.w};
#pragma unroll
    for (int j = 0; j < 8; ++j) {
      short h, l;
      split_bf16(av[j], h, l);     Ah0[j] = h; Al0[j] = l;
      split_bf16(av[8 + j], h, l); Ah1[j] = h; Al1[j] = l;
    }
  }

  float sv[4][8]; int iv[4][8];
#pragma unroll
  for (int r = 0; r < 4; ++r)
#pragma unroll
    for (int k = 0; k < 8; ++k) { sv[r][k] = -1e30f; iv[r][k] = 0; }

  const short* bh;
  const short* bl;
  int iters, ngb;
  if (is_mem) {
    bh = whi + (size_t)(ch * 64) * D_;   // W shared across batch
    bl = wlo + (size_t)(ch * 64) * D_;
    iters = 4;  ngb = ch * 64;
  } else {
    const size_t bofs = ((size_t)(b * NP_TOT) + ch * 512) * D_;
    bh = phi + bofs;  bl = plo + bofs;
    iters = 32; ngb = ch * 512;
  }

#pragma unroll 2
  for (int it = 0; it < iters; ++it) {
    const int nr = it * 16 + sub;
    const short* rh = bh + nr * D_;
    const short* rl = bl + nr * D_;
    bb8 Bh0 = *(const bb8*)(rh + quad * 8);
    bb8 Bh1 = *(const bb8*)(rh + 32 + quad * 8);
    bb8 Bl0 = *(const bb8*)(rl + quad * 8);
    bb8 Bl1 = *(const bb8*)(rl + 32 + quad * 8);
    f32x4 acc = {0.f, 0.f, 0.f, 0.f};
    if (is_mem) {   // wave-uniform; extra lo*lo terms -> 4-term (exact products)
      acc = __builtin_amdgcn_mfma_f32_16x16x32_bf16(Al0, Bl0, acc, 0, 0, 0);
      acc = __builtin_amdgcn_mfma_f32_16x16x32_bf16(Al1, Bl1, acc, 0, 0, 0);
    }
    acc = __builtin_amdgcn_mfma_f32_16x16x32_bf16(Al0, Bh0, acc, 0, 0, 0);
    acc = __builtin_amdgcn_mfma_f32_16x16x32_bf16(Al1, Bh1, acc, 0, 0, 0);
    acc = __builtin_amdgcn_mfma_f32_16x16x32_bf16(Ah0, Bl0, acc, 0, 0, 0);
    acc = __builtin_amdgcn_mfma_f32_16x16x32_bf16(Ah1, Bl1, acc, 0, 0, 0);
    acc = __builtin_amdgcn_mfma_f32_16x16x32_bf16(Ah0, Bh0, acc, 0, 0, 0);
    acc = __builtin_amdgcn_mfma_f32_16x16x32_bf16(Ah1, Bh1, acc, 0, 0, 0);
    const int ng = ngb + nr;
#pragma unroll
    for (int r = 0; r < 4; ++r) {
      float sc = acc[r];
      if (sc > sv[r][7]) insert8(sc, ng, sv[r], iv[r]);
    }
  }

  float* osc = is_mem ? ws_mem_sc : ws_pts_sc;
  int*   oix = is_mem ? ws_mem_ix : ws_pts_ix;

  const int pbase = pt * 64 + wv * 16 + quad * 4;
#pragma unroll
  for (int r = 0; r < 4; ++r) {
    const int pg = pbase + r;
    float out_s = 0.f; int out_i = 0;
#pragma unroll
    for (int k = 0; k < 8; ++k) {
      unsigned fb = __float_as_uint(sv[r][0]);
      unsigned mk = (fb & 0x80000000u) ? ~fb : (fb | 0x80000000u);
      unsigned key = (mk & 0xFFFFFFF0u) | (unsigned)sub;
#pragma unroll
      for (int off = 1; off < 16; off <<= 1) {
        unsigned ok = (unsigned)__shfl_xor((int)key, off);
        key = key > ok ? key : ok;
      }
      const int wsub = (int)(key & 15u);
      const int wlane = (lane & 48) | wsub;
      float wsc = __shfl(sv[r][0], wlane);
      int   wix = __shfl(iv[r][0], wlane);
      if (sub == wsub) {
#pragma unroll
        for (int i2 = 0; i2 < 7; ++i2) { sv[r][i2] = sv[r][i2 + 1]; iv[r][i2] = iv[r][i2 + 1]; }
        sv[r][7] = -1e30f;
      }
      if (sub == k) { out_s = wsc; out_i = wix; }
    }
    if (sub < 8 && pg < P_TOT) {
      const size_t base = ((size_t)(b * P_TOT) + pg) * 64 + ch * 8 + sub;
      osc[base] = out_s; oix[base] = out_i;
    }
  }
}

// Merged finalize: grid.y = 0 -> points branch, 1 -> memory branch.
// Per-branch arithmetic FROZEN since R1.
__global__ __launch_bounds__(256) void finalize2(
    const float* __restrict__ points, const float* __restrict__ W,
    const float* __restrict__ ws_sc_p, const int* __restrict__ ws_ix_p,
    const float* __restrict__ ws_sc_m, const int* __restrict__ ws_ix_m,
    float* __restrict__ out_p, float* __restrict__ out_m)
{
  const int tid = threadIdx.x;
  const int lane = tid & 63, wv = tid >> 6;
  const int gp = blockIdx.x * 4 + wv;
  const int b = (gp >= P_TOT) ? 1 : 0;
  const size_t cb = (size_t)gp * 64;
  const bool mem = (blockIdx.y == 1);

  const float* ws_sc = mem ? ws_sc_m : ws_sc_p;
  const int*   ws_ix = mem ? ws_ix_m : ws_ix_p;
  const float* sb    = mem ? W : (points + (size_t)b * (NP_TOT * D_));
  float*       outp  = mem ? out_m : out_p;

  float ss = ws_sc[cb + lane];
  const int myix = ws_ix[cb + lane];

  float wsc[8]; int wix[8];
#pragma unroll
  for (int k = 0; k < 8; ++k) {
    float cv = ss; int cl = lane;
#pragma unroll
    for (int off = 32; off >= 1; off >>= 1) {
      float ov = __shfl_xor(cv, off);
      int   ol = __shfl_xor(cl, off);
      if (ov > cv || (ov == cv && ol < cl)) { cv = ov; cl = ol; }
    }
    wsc[k] = cv;
    wix[k] = __shfl(myix, cl);
    if (lane == cl) ss = -1e30f;
  }

  const float m = wsc[0];
  float e[8], Z = 0.f;
#pragma unroll
  for (int k = 0; k < 8; ++k) { e[k] = expf(wsc[k] - m); Z += e[k]; }
  const float inv = 1.0f / Z;

  float acc = 0.f;
#pragma unroll
  for (int k = 0; k < 8; ++k)
    acc = fmaf(e[k] * inv, sb[(size_t)wix[k] * 64 + lane], acc);
  outp[cb + lane] = acc;
}

// Scatter R7: channel-blocked. Grid (210, 4, 2); each thread owns 4 cells
// (one owner int4) x 16 channels (blockIdx.y*16 .. +16). Per (cell,source)
// the 64 B row segment is read as 4x f32x4 (exactly ONE cache line,
// amplification 16x -> 1x vs the per-channel dword gather of R5), then a
// register 4x4 transpose per channel-quad feeds the SAME j4-coalesced
// nontemporal store pattern as R5. owner read 4x not 64x. Value semantics
// identical to R5 (max-owner, zero for empty, all-empty skip).
__global__ __launch_bounds__(256) void scatter5(
    const float* __restrict__ pillars, const float* __restrict__ scale,
    const float* __restrict__ pos_point, const float* __restrict__ pos_mem,
    const int* __restrict__ owner, float* __restrict__ out)
{
  const int j4 = blockIdx.x * 256 + threadIdx.x;
  if (j4 >= J4) return;
  const int cbch = blockIdx.y * 16;   // channel base: this thread's 16 channels
  const int b = blockIdx.z;

  const int4 own = ((const int4*)owner)[(size_t)b * J4 + j4];
  const bool act = (own.x & own.y & own.z & own.w) >= 0;  // any cell occupied

  const size_t bo = (size_t)b * (P_TOT * D_);
  const float* sp = pillars   + bo;
  const float* sm = pos_mem   + bo;
  const float* sq = pos_point + bo;
  const float* ss = scale     + bo;

  const size_t r0 = (size_t)(own.x < 0 ? 0 : own.x) * 64 + cbch;
  const size_t r1 = (size_t)(own.y < 0 ? 0 : own.y) * 64 + cbch;
  const size_t r2 = (size_t)(own.z < 0 ? 0 : own.z) * 64 + cbch;
  const size_t r3 = (size_t)(own.w < 0 ? 0 : own.w) * 64 + cbch;

  f32x4* o4 = (f32x4*)out;
  const f32x4 zf = {0.f, 0.f, 0.f, 0.f};

#pragma unroll
  for (int q = 0; q < 4; ++q) {
    const int ch = cbch + q * 4;   // first of 4 channels this quad covers

    // ---- pillars -> O0 rows [ch..ch+4) and O1 rows [ch..ch+4) ----
    {
      f32x4 A0 = zf, A1 = zf, A2 = zf, A3 = zf;
      if (act) {
        A0 = own.x < 0 ? zf : *(const f32x4*)(sp + r0 + q * 4);
        A1 = own.y < 0 ? zf : *(const f32x4*)(sp + r1 + q * 4);
        A2 = own.z < 0 ? zf : *(const f32x4*)(sp + r2 + q * 4);
        A3 = own.w < 0 ? zf : *(const f32x4*)(sp + r3 + q * 4);
      }
#pragma unroll
      for (int dc = 0; dc < 4; ++dc) {
        f32x4 v = {A0[dc], A1[dc], A2[dc], A3[dc]};
        __builtin_nontemporal_store(v, o4 + (size_t)(b * 128 + ch + dc) * J4 + j4);
        __builtin_nontemporal_store(v, o4 + 13713408UL + (size_t)(b * 128 + ch + dc) * J4 + j4);
      }
    }
    // ---- pos_mem -> O0 rows [64+ch..64+ch+4) ----
    {
      f32x4 A0 = zf, A1 = zf, A2 = zf, A3 = zf;
      if (act) {
        A0 = own.x < 0 ? zf : *(const f32x4*)(sm + r0 + q * 4);
        A1 = own.y < 0 ? zf : *(const f32x4*)(sm + r1 + q * 4);
        A2 = own.z < 0 ? zf : *(const f32x4*)(sm + r2 + q * 4);
        A3 = own.w < 0 ? zf : *(const f32x4*)(sm + r3 + q * 4);
      }
#pragma unroll
      for (int dc = 0; dc < 4; ++dc) {
        f32x4 v = {A0[dc], A1[dc], A2[dc], A3[dc]};
        __builtin_nontemporal_store(v, o4 + (size_t)(b * 128 + 64 + ch + dc) * J4 + j4);
      }
    }
    // ---- pos_point -> O1 rows [64+ch..64+ch+4) ----
    {
      f32x4 A0 = zf, A1 = zf, A2 = zf, A3 = zf;
      if (act) {
        A0 = own.x < 0 ? zf : *(const f32x4*)(sq + r0 + q * 4);
        A1 = own.y < 0 ? zf : *(const f32x4*)(sq + r1 + q * 4);
        A2 = own.z < 0 ? zf : *(const f32x4*)(sq + r2 + q * 4);
        A3 = own.w < 0 ? zf : *(const f32x4*)(sq + r3 + q * 4);
      }
#pragma unroll
      for (int dc = 0; dc < 4; ++dc) {
        f32x4 v = {A0[dc], A1[dc], A2[dc], A3[dc]};
        __builtin_nontemporal_store(v, o4 + 13713408UL + (size_t)(b * 128 + 64 + ch + dc) * J4 + j4);
      }
    }
    // ---- scale -> O2 rows [ch..ch+4) ----
    {
      f32x4 A0 = zf, A1 = zf, A2 = zf, A3 = zf;
      if (act) {
        A0 = own.x < 0 ? zf : *(const f32x4*)(ss + r0 + q * 4);
        A1 = own.y < 0 ? zf : *(const f32x4*)(ss + r1 + q * 4);
        A2 = own.z < 0 ? zf : *(const f32x4*)(ss + r2 + q * 4);
        A3 = own.w < 0 ? zf : *(const f32x4*)(ss + r3 + q * 4);
      }
#pragma unroll
      for (int dc = 0; dc < 4; ++dc) {
        f32x4 v = {A0[dc], A1[dc], A2[dc], A3[dc]};
        __builtin_nontemporal_store(v, o4 + 27426816UL + (size_t)(b * 64 + ch + dc) * J4 + j4);
      }
    }
  }
}

extern "C" void kernel_launch(void* const* d_in, const int* in_sizes, int n_in,
                              void* d_out, int out_size, void* d_ws, size_t ws_size,
                              hipStream_t stream) {
  const float* pillars = (const float*)d_in[0];   // [2,4000,64]
  const float* scale   = (const float*)d_in[1];   // [2,4000,64]
  const float* points  = (const float*)d_in[2];   // [2,4096,64]
  const float* W       = (const float*)d_in[3];   // [512,64]
  const int*   indices = (const int*)d_in[4];     // [2,4000]
  float* out = (float*)d_out;

  // ws layout (int units): pts cand 4x512000, owner 428544, bf16 planes
  float* ws_pts_sc = (float*)d_ws;
  int*   ws_pts_ix = (int*)d_ws + 512000;
  float* ws_mem_sc = (float*)d_ws + 1024000;
  int*   ws_mem_ix = (int*)d_ws + 1536000;
  int*   owner     = (int*)d_ws + 2048000;
  short* phi       = (short*)((int*)d_ws + 2480000);  // 524288 shorts
  short* plo       = (short*)((int*)d_ws + 2760000);  // 524288 shorts
  short* whi       = (short*)((int*)d_ws + 3030000);  // 32768 shorts
  short* wlo       = (short*)((int*)d_ws + 3050000);  // 32768 shorts

  (void)hipMemsetAsync(owner, 0xFF, (size_t)B_ * HW_TOT * sizeof(int), stream);

  // fused cvt points (512 blocks) + build_owner (32) + cvt W (32)
  prep<<<576, 256, 0, stream>>>(points, phi, plo, indices, owner, W, whi, wlo);

  // both top-k branches in one zero-LDS kernel:
  // y in [0,8) = points chunks of 512; y in [8,16) = memory chunks of 64
  topk_mfma<<<dim3(63, 16, 2), 256, 0, stream>>>(
      pillars, phi, plo, whi, wlo, ws_pts_sc, ws_pts_ix, ws_mem_sc, ws_mem_ix);

  // both branches' merge+softmax+gather in one launch
  finalize2<<<dim3(2000, 2), 256, 0, stream>>>(
      points, W, ws_pts_sc, ws_pts_ix, ws_mem_sc, ws_mem_ix, out + O3, out + O4);

  // channel-blocked scatter: 16 channels per thread, one owner read per 4 cells
  scatter5<<<dim3(210, 4, 2), 256, 0, stream>>>(
      pillars, scale, out + O3, out + O4, owner, out);
}

// Round 3
// 632.290 us; speedup vs baseline: 1.0445x; 1.0445x over previous
//
#include <hip/hip_runtime.h>

// Problem constants
#define B_     2
#define P_TOT  4000
#define NP_TOT 4096
#define D_     64
#define M_     512
#define HW_TOT 214272   // 496*432
#define J4     53568    // HW/4

// Output offsets (in floats, concatenated return order)
#define O0 0UL            // spatial_features        [2,128,HW]
#define O1 54853632UL     // spatial_features_point  [2,128,HW]
#define O2 109707264UL    // spatial_scale_features  [2,64,HW]
#define O3 137134080UL    // point_positive_features [8000,64]
#define O4 137646080UL    // memory_positive_features[8000,64]

typedef __attribute__((ext_vector_type(8))) short bb8;
typedef __attribute__((ext_vector_type(4))) float f32x4;

// Sorted-descending insert into top-8 registers (caller guards with sc > s[7])
__device__ __forceinline__ void insert8(float sc, int n, float s[8], int ix[8]) {
  float cs = sc; int ci = n;
#pragma unroll
  for (int i = 0; i < 8; ++i) {
    bool gt = cs > s[i];
    float ts = s[i]; int ti = ix[i];
    s[i]  = gt ? cs : ts;  ix[i] = gt ? ci : ti;
    cs    = gt ? ts : cs;  ci    = gt ? ti : ci;
  }
}

__device__ __forceinline__ void split_bf16(float x, short& h, short& l) {
  unsigned fb = __float_as_uint(x);
  unsigned hb = fb & 0xFFFF0000u;          // truncate to bf16 (hi plane)
  float lof = x - __uint_as_float(hb);     // residual
  h = (short)(hb >> 16);
  l = (short)(__float_as_uint(lof) >> 16); // bf16 of residual (lo plane)
}

// prep: fused [cvt points planes (blocks 0..511)] + [build_owner (512..543)]
//       + [cvt W planes (544..575)]. cvt arithmetic FROZEN since R2.
__global__ __launch_bounds__(256) void prep(
    const float* __restrict__ points, short* __restrict__ hi, short* __restrict__ lo,
    const int* __restrict__ indices, int* __restrict__ owner,
    const float* __restrict__ W, short* __restrict__ whi, short* __restrict__ wlo)
{
  if (blockIdx.x < 512) {
    int t = blockIdx.x * 256 + threadIdx.x;           // n4 = 131072 exactly
    float4 v = ((const float4*)points)[t];
    float x[4] = {v.x, v.y, v.z, v.w};
    short h[4], l[4];
#pragma unroll
    for (int j = 0; j < 4; ++j) split_bf16(x[j], h[j], l[j]);
    ((short4*)hi)[t] = make_short4(h[0], h[1], h[2], h[3]);
    ((short4*)lo)[t] = make_short4(l[0], l[1], l[2], l[3]);
  } else if (blockIdx.x < 544) {
    int t = (blockIdx.x - 512) * 256 + threadIdx.x;
    if (t >= B_ * P_TOT) return;
    int b = (t >= P_TOT) ? 1 : 0;
    int p = t - b * P_TOT;
    atomicMax(&owner[b * HW_TOT + indices[t]], p);
  } else {
    int t = (blockIdx.x - 544) * 256 + threadIdx.x;   // n4 = 8192 exactly
    float4 v = ((const float4*)W)[t];
    float x[4] = {v.x, v.y, v.z, v.w};
    short h[4], l[4];
#pragma unroll
    for (int j = 0; j < 4; ++j) split_bf16(x[j], h[j], l[j]);
    ((short4*)whi)[t] = make_short4(h[0], h[1], h[2], h[3]);
    ((short4*)wlo)[t] = make_short4(l[0], l[1], l[2], l[3]);
  }
}

// R8: topk (both branches, arithmetic FROZEN) FUSED with the static 3/5 of the
// scatter (pillars->O0, pillars->O1, scale->O2 = 329 MB of stores that depend
// only on owner+inputs). Store-bound scatter blocks co-run with MFMA/VALU-bound
// topk blocks on different pipes. Block space: 1848 = 168 groups of 11
// (6 topk : 5 scatter interleaved; 168*6=1008 topk, 168*5=840 scatter).
__global__ __launch_bounds__(256) void topk_sstat(
    const float* __restrict__ pillars, const float* __restrict__ scale,
    const short* __restrict__ phi, const short* __restrict__ plo,
    const short* __restrict__ whi, const short* __restrict__ wlo,
    const int* __restrict__ owner,
    float* __restrict__ ws_pts_sc, int* __restrict__ ws_pts_ix,
    float* __restrict__ ws_mem_sc, int* __restrict__ ws_mem_ix,
    float* __restrict__ out)
{
  const int g = blockIdx.x / 11, r11 = blockIdx.x % 11;
  const int b = blockIdx.z;

  if (r11 >= 6) {
    // ---------------- static scatter: pillars + scale planes ----------------
    const int six = g * 5 + (r11 - 6);          // [0, 840)
    const int jblk = six % 210, ych = six / 210;
    const int j4 = jblk * 256 + threadIdx.x;
    if (j4 >= J4) return;
    const int cbch = ych * 16;

    const int4 own = ((const int4*)owner)[(size_t)b * J4 + j4];
    const bool act = (own.x & own.y & own.z & own.w) >= 0;

    const size_t bo = (size_t)b * (P_TOT * D_);
    const float* sp = pillars + bo;
    const float* ssc = scale  + bo;

    const size_t r0 = (size_t)(own.x < 0 ? 0 : own.x) * 64 + cbch;
    const size_t r1 = (size_t)(own.y < 0 ? 0 : own.y) * 64 + cbch;
    const size_t r2 = (size_t)(own.z < 0 ? 0 : own.z) * 64 + cbch;
    const size_t r3 = (size_t)(own.w < 0 ? 0 : own.w) * 64 + cbch;

    f32x4* o4 = (f32x4*)out;
    const f32x4 zf = {0.f, 0.f, 0.f, 0.f};

#pragma unroll
    for (int q = 0; q < 4; ++q) {
      const int ch = cbch + q * 4;
      {
        f32x4 A0 = zf, A1 = zf, A2 = zf, A3 = zf;
        if (act) {
          A0 = own.x < 0 ? zf : *(const f32x4*)(sp + r0 + q * 4);
          A1 = own.y < 0 ? zf : *(const f32x4*)(sp + r1 + q * 4);
          A2 = own.z < 0 ? zf : *(const f32x4*)(sp + r2 + q * 4);
          A3 = own.w < 0 ? zf : *(const f32x4*)(sp + r3 + q * 4);
        }
#pragma unroll
        for (int dc = 0; dc < 4; ++dc) {
          f32x4 v = {A0[dc], A1[dc], A2[dc], A3[dc]};
          __builtin_nontemporal_store(v, o4 + (size_t)(b * 128 + ch + dc) * J4 + j4);
          __builtin_nontemporal_store(v, o4 + 13713408UL + (size_t)(b * 128 + ch + dc) * J4 + j4);
        }
      }
      {
        f32x4 A0 = zf, A1 = zf, A2 = zf, A3 = zf;
        if (act) {
          A0 = own.x < 0 ? zf : *(const f32x4*)(ssc + r0 + q * 4);
          A1 = own.y < 0 ? zf : *(const f32x4*)(ssc + r1 + q * 4);
          A2 = own.z < 0 ? zf : *(const f32x4*)(ssc + r2 + q * 4);
          A3 = own.w < 0 ? zf : *(const f32x4*)(ssc + r3 + q * 4);
        }
#pragma unroll
        for (int dc = 0; dc < 4; ++dc) {
          f32x4 v = {A0[dc], A1[dc], A2[dc], A3[dc]};
          __builtin_nontemporal_store(v, o4 + 27426816UL + (size_t)(b * 64 + ch + dc) * J4 + j4);
        }
      }
    }
    return;
  }

  // ---------------- topk (arithmetic identical to R7) ----------------
  const int tix = g * 6 + r11;                  // [0, 1008)
  const int pt = tix % 63, chy = tix / 63;
  const int tid = threadIdx.x;
  const bool is_mem = chy >= 8;
  const int ch = is_mem ? (chy - 8) : chy;
  const int lane = tid & 63, wv = tid >> 6;
  const int sub = lane & 15, quad = lane >> 4;

  int prow = pt * 64 + wv * 16 + sub;
  if (prow >= P_TOT) prow = P_TOT - 1;
  const float* ap = pillars + ((size_t)(b * P_TOT) + prow) * D_;
  bb8 Ah0, Ah1, Al0, Al1;
  {
    const float4* a4 = (const float4*)(ap + quad * 8);
    const float4* b4 = (const float4*)(ap + 32 + quad * 8);
    float4 t0 = a4[0], t1 = a4[1], t2 = b4[0], t3 = b4[1];
    float av[16] = {t0.x, t0.y, t0.z, t0.w, t1.x, t1.y, t1.z, t1.w,
                    t2.x, t2.y, t2.z, t2.w, t3.x, t3.y, t3.z, t3.w};
#pragma unroll
    for (int j = 0; j < 8; ++j) {
      short h, l;
      split_bf16(av[j], h, l);     Ah0[j] = h; Al0[j] = l;
      split_bf16(av[8 + j], h, l); Ah1[j] = h; Al1[j] = l;
    }
  }

  float sv[4][8]; int iv[4][8];
#pragma unroll
  for (int r = 0; r < 4; ++r)
#pragma unroll
    for (int k = 0; k < 8; ++k) { sv[r][k] = -1e30f; iv[r][k] = 0; }

  const short* bh;
  const short* bl;
  int iters, ngb;
  if (is_mem) {
    bh = whi + (size_t)(ch * 64) * D_;   // W shared across batch
    bl = wlo + (size_t)(ch * 64) * D_;
    iters = 4;  ngb = ch * 64;
  } else {
    const size_t bofs = ((size_t)(b * NP_TOT) + ch * 512) * D_;
    bh = phi + bofs;  bl = plo + bofs;
    iters = 32; ngb = ch * 512;
  }

#pragma unroll 2
  for (int it = 0; it < iters; ++it) {
    const int nr = it * 16 + sub;
    const short* rh = bh + nr * D_;
    const short* rl = bl + nr * D_;
    bb8 Bh0 = *(const bb8*)(rh + quad * 8);
    bb8 Bh1 = *(const bb8*)(rh + 32 + quad * 8);
    bb8 Bl0 = *(const bb8*)(rl + quad * 8);
    bb8 Bl1 = *(const bb8*)(rl + 32 + quad * 8);
    f32x4 acc = {0.f, 0.f, 0.f, 0.f};
    if (is_mem) {   // wave-uniform; extra lo*lo terms -> 4-term (exact products)
      acc = __builtin_amdgcn_mfma_f32_16x16x32_bf16(Al0, Bl0, acc, 0, 0, 0);
      acc = __builtin_amdgcn_mfma_f32_16x16x32_bf16(Al1, Bl1, acc, 0, 0, 0);
    }
    acc = __builtin_amdgcn_mfma_f32_16x16x32_bf16(Al0, Bh0, acc, 0, 0, 0);
    acc = __builtin_amdgcn_mfma_f32_16x16x32_bf16(Al1, Bh1, acc, 0, 0, 0);
    acc = __builtin_amdgcn_mfma_f32_16x16x32_bf16(Ah0, Bl0, acc, 0, 0, 0);
    acc = __builtin_amdgcn_mfma_f32_16x16x32_bf16(Ah1, Bl1, acc, 0, 0, 0);
    acc = __builtin_amdgcn_mfma_f32_16x16x32_bf16(Ah0, Bh0, acc, 0, 0, 0);
    acc = __builtin_amdgcn_mfma_f32_16x16x32_bf16(Ah1, Bh1, acc, 0, 0, 0);
    const int ng = ngb + nr;
#pragma unroll
    for (int r = 0; r < 4; ++r) {
      float sc = acc[r];
      if (sc > sv[r][7]) insert8(sc, ng, sv[r], iv[r]);
    }
  }

  float* osc = is_mem ? ws_mem_sc : ws_pts_sc;
  int*   oix = is_mem ? ws_mem_ix : ws_pts_ix;

  const int pbase = pt * 64 + wv * 16 + quad * 4;
#pragma unroll
  for (int r = 0; r < 4; ++r) {
    const int pg = pbase + r;
    float out_s = 0.f; int out_i = 0;
#pragma unroll
    for (int k = 0; k < 8; ++k) {
      unsigned fb = __float_as_uint(sv[r][0]);
      unsigned mk = (fb & 0x80000000u) ? ~fb : (fb | 0x80000000u);
      unsigned key = (mk & 0xFFFFFFF0u) | (unsigned)sub;
#pragma unroll
      for (int off = 1; off < 16; off <<= 1) {
        unsigned ok = (unsigned)__shfl_xor((int)key, off);
        key = key > ok ? key : ok;
      }
      const int wsub = (int)(key & 15u);
      const int wlane = (lane & 48) | wsub;
      float wsc = __shfl(sv[r][0], wlane);
      int   wix = __shfl(iv[r][0], wlane);
      if (sub == wsub) {
#pragma unroll
        for (int i2 = 0; i2 < 7; ++i2) { sv[r][i2] = sv[r][i2 + 1]; iv[r][i2] = iv[r][i2 + 1]; }
        sv[r][7] = -1e30f;
      }
      if (sub == k) { out_s = wsc; out_i = wix; }
    }
    if (sub < 8 && pg < P_TOT) {
      const size_t base = ((size_t)(b * P_TOT) + pg) * 64 + ch * 8 + sub;
      osc[base] = out_s; oix[base] = out_i;
    }
  }
}

// Merged finalize: grid.y = 0 -> points branch, 1 -> memory branch.
// Per-branch arithmetic FROZEN since R1.
__global__ __launch_bounds__(256) void finalize2(
    const float* __restrict__ points, const float* __restrict__ W,
    const float* __restrict__ ws_sc_p, const int* __restrict__ ws_ix_p,
    const float* __restrict__ ws_sc_m, const int* __restrict__ ws_ix_m,
    float* __restrict__ out_p, float* __restrict__ out_m)
{
  const int tid = threadIdx.x;
  const int lane = tid & 63, wv = tid >> 6;
  const int gp = blockIdx.x * 4 + wv;
  const int b = (gp >= P_TOT) ? 1 : 0;
  const size_t cb = (size_t)gp * 64;
  const bool mem = (blockIdx.y == 1);

  const float* ws_sc = mem ? ws_sc_m : ws_sc_p;
  const int*   ws_ix = mem ? ws_ix_m : ws_ix_p;
  const float* sb    = mem ? W : (points + (size_t)b * (NP_TOT * D_));
  float*       outp  = mem ? out_m : out_p;

  float ss = ws_sc[cb + lane];
  const int myix = ws_ix[cb + lane];

  float wsc[8]; int wix[8];
#pragma unroll
  for (int k = 0; k < 8; ++k) {
    float cv = ss; int cl = lane;
#pragma unroll
    for (int off = 32; off >= 1; off >>= 1) {
      float ov = __shfl_xor(cv, off);
      int   ol = __shfl_xor(cl, off);
      if (ov > cv || (ov == cv && ol < cl)) { cv = ov; cl = ol; }
    }
    wsc[k] = cv;
    wix[k] = __shfl(myix, cl);
    if (lane == cl) ss = -1e30f;
  }

  const float m = wsc[0];
  float e[8], Z = 0.f;
#pragma unroll
  for (int k = 0; k < 8; ++k) { e[k] = expf(wsc[k] - m); Z += e[k]; }
  const float inv = 1.0f / Z;

  float acc = 0.f;
#pragma unroll
  for (int k = 0; k < 8; ++k)
    acc = fmaf(e[k] * inv, sb[(size_t)wix[k] * 64 + lane], acc);
  outp[cb + lane] = acc;
}

// Dynamic scatter: only the two finalize-dependent planes
// (pos_mem -> O0 rows [64,128), pos_point -> O1 rows [64,128) = 219 MB).
__global__ __launch_bounds__(256) void scatter_dyn(
    const float* __restrict__ pos_point, const float* __restrict__ pos_mem,
    const int* __restrict__ owner, float* __restrict__ out)
{
  const int j4 = blockIdx.x * 256 + threadIdx.x;
  if (j4 >= J4) return;
  const int cbch = blockIdx.y * 16;
  const int b = blockIdx.z;

  const int4 own = ((const int4*)owner)[(size_t)b * J4 + j4];
  const bool act = (own.x & own.y & own.z & own.w) >= 0;

  const size_t bo = (size_t)b * (P_TOT * D_);
  const float* sm = pos_mem   + bo;
  const float* sq = pos_point + bo;

  const size_t r0 = (size_t)(own.x < 0 ? 0 : own.x) * 64 + cbch;
  const size_t r1 = (size_t)(own.y < 0 ? 0 : own.y) * 64 + cbch;
  const size_t r2 = (size_t)(own.z < 0 ? 0 : own.z) * 64 + cbch;
  const size_t r3 = (size_t)(own.w < 0 ? 0 : own.w) * 64 + cbch;

  f32x4* o4 = (f32x4*)out;
  const f32x4 zf = {0.f, 0.f, 0.f, 0.f};

#pragma unroll
  for (int q = 0; q < 4; ++q) {
    const int ch = cbch + q * 4;
    {
      f32x4 A0 = zf, A1 = zf, A2 = zf, A3 = zf;
      if (act) {
        A0 = own.x < 0 ? zf : *(const f32x4*)(sm + r0 + q * 4);
        A1 = own.y < 0 ? zf : *(const f32x4*)(sm + r1 + q * 4);
        A2 = own.z < 0 ? zf : *(const f32x4*)(sm + r2 + q * 4);
        A3 = own.w < 0 ? zf : *(const f32x4*)(sm + r3 + q * 4);
      }
#pragma unroll
      for (int dc = 0; dc < 4; ++dc) {
        f32x4 v = {A0[dc], A1[dc], A2[dc], A3[dc]};
        __builtin_nontemporal_store(v, o4 + (size_t)(b * 128 + 64 + ch + dc) * J4 + j4);
      }
    }
    {
      f32x4 A0 = zf, A1 = zf, A2 = zf, A3 = zf;
      if (act) {
        A0 = own.x < 0 ? zf : *(const f32x4*)(sq + r0 + q * 4);
        A1 = own.y < 0 ? zf : *(const f32x4*)(sq + r1 + q * 4);
        A2 = own.z < 0 ? zf : *(const f32x4*)(sq + r2 + q * 4);
        A3 = own.w < 0 ? zf : *(const f32x4*)(sq + r3 + q * 4);
      }
#pragma unroll
      for (int dc = 0; dc < 4; ++dc) {
        f32x4 v = {A0[dc], A1[dc], A2[dc], A3[dc]};
        __builtin_nontemporal_store(v, o4 + 13713408UL + (size_t)(b * 128 + 64 + ch + dc) * J4 + j4);
      }
    }
  }
}

extern "C" void kernel_launch(void* const* d_in, const int* in_sizes, int n_in,
                              void* d_out, int out_size, void* d_ws, size_t ws_size,
                              hipStream_t stream) {
  const float* pillars = (const float*)d_in[0];   // [2,4000,64]
  const float* scale   = (const float*)d_in[1];   // [2,4000,64]
  const float* points  = (const float*)d_in[2];   // [2,4096,64]
  const float* W       = (const float*)d_in[3];   // [512,64]
  const int*   indices = (const int*)d_in[4];     // [2,4000]
  float* out = (float*)d_out;

  // ws layout (int units): pts cand 4x512000, owner 428544, bf16 planes
  float* ws_pts_sc = (float*)d_ws;
  int*   ws_pts_ix = (int*)d_ws + 512000;
  float* ws_mem_sc = (float*)d_ws + 1024000;
  int*   ws_mem_ix = (int*)d_ws + 1536000;
  int*   owner     = (int*)d_ws + 2048000;
  short* phi       = (short*)((int*)d_ws + 2480000);  // 524288 shorts
  short* plo       = (short*)((int*)d_ws + 2760000);  // 524288 shorts
  short* whi       = (short*)((int*)d_ws + 3030000);  // 32768 shorts
  short* wlo       = (short*)((int*)d_ws + 3050000);  // 32768 shorts

  (void)hipMemsetAsync(owner, 0xFF, (size_t)B_ * HW_TOT * sizeof(int), stream);

  // fused cvt points (512 blocks) + build_owner (32) + cvt W (32)
  prep<<<576, 256, 0, stream>>>(points, phi, plo, indices, owner, W, whi, wlo);

  // fused: topk both branches (1008 blocks) + static scatter planes (840
  // blocks), interleaved 6:5 within each group of 11 -> store/compute overlap
  topk_sstat<<<dim3(1848, 1, 2), 256, 0, stream>>>(
      pillars, scale, phi, plo, whi, wlo, owner,
      ws_pts_sc, ws_pts_ix, ws_mem_sc, ws_mem_ix, out);

  // both branches' merge+softmax+gather in one launch
  finalize2<<<dim3(2000, 2), 256, 0, stream>>>(
      points, W, ws_pts_sc, ws_pts_ix, ws_mem_sc, ws_mem_ix, out + O3, out + O4);

  // dynamic planes only (pos_mem -> O0, pos_point -> O1)
  scatter_dyn<<<dim3(210, 4, 2), 256, 0, stream>>>(
      out + O3, out + O4, owner, out);
}